// Round 4
// baseline (209.850 us; speedup 1.0000x reference)
//
#include <hip/hip_runtime.h>
#include <hip/hip_bf16.h>
#include <stdint.h>

#define NP 30000
#define BBINS 80
#define INCH 16
#define OUTCH 32
#define KDIM 1280       // BBINS*INCH
#define NDIM 512        // OUTCH*TBINS
#define KSTEPS 40       // KDIM/32
#define NROWS (NP * BBINS)   // 2,400,000

typedef __bf16 bf16x8 __attribute__((ext_vector_type(8)));
typedef __bf16 bf16x4 __attribute__((ext_vector_type(4)));
typedef float f32x4 __attribute__((ext_vector_type(4)));

__device__ __forceinline__ void async_ld16(const void* g, void* l) {
    __builtin_amdgcn_global_load_lds(
        (const __attribute__((address_space(1))) unsigned int*)g,
        (__attribute__((address_space(3))) unsigned int*)l,
        16, 0, 0);
}

// ---------------------------------------------------------------------------
// Prep: PW[kc][n][slot][e] bf16; slot s holds data k-chunk s ^ ((n>>1)&3)
// (conflict-free ds_read_b128 B fragments). lw[k][n] = W[(b+5t)%80][c][o],
// k=b*16+c, n=o*16+t.
// ---------------------------------------------------------------------------
__global__ void prep_weights(const float* __restrict__ w, __bf16* __restrict__ pw) {
    int gid = blockIdx.x * 256 + threadIdx.x;           // 655360 total
    int e  = gid & 7;
    int qs = (gid >> 3) & 3;                             // slot
    int n  = (gid >> 5) & 511;
    int kc = gid >> 14;                                  // 0..39
    int kp = kc * 32 + ((qs ^ ((n >> 1) & 3)) << 3) + e; // data k index
    int b = kp >> 4, c = kp & 15;
    int o = n >> 4,  t = n & 15;
    int bid = (b + 5 * t) % BBINS;
    pw[gid] = (__bf16)w[(bid * INCH + c) * OUTCH + o];
}

// ---------------------------------------------------------------------------
// Gather: block = 256 threads <-> 64 rows (4 lanes/row). Conn staged to LDS
// with coalesced dwordx4 (0.19 VMEM/lane), broadcast-read back. x loads:
// 4 contiguous lanes per 64-B x row -> 16 lines/instr. h written in the
// GEMM-ready swizzled layout: chunk c of patch p's row stored at slot
// (c&~3) | ((c&3) ^ ((p>>1)&3)).  Stores remain full-line coalesced.
// ---------------------------------------------------------------------------
__global__ __launch_bounds__(256) void gather_h(
    const float* __restrict__ x,
    const int*   __restrict__ cidx,
    const float* __restrict__ cval,
    __bf16* __restrict__ h) {
    __shared__ int   ci[192];
    __shared__ float cv[192];
    const int t  = threadIdx.x;
    const int r0 = blockIdx.x * 64;

    if (t < 48)
        ((int4*)ci)[t] = ((const int4*)(cidx + (size_t)r0 * 3))[t];
    else if (t >= 64 && t < 112)
        ((float4*)cv)[t - 64] = ((const float4*)(cval + (size_t)r0 * 3))[t - 64];
    __syncthreads();

    const int rl = t >> 2;               // 0..63
    const int q  = t & 3;                // channel quad
    const int i0 = ci[rl * 3 + 0], i1 = ci[rl * 3 + 1], i2 = ci[rl * 3 + 2];
    const float v0 = cv[rl * 3 + 0], v1 = cv[rl * 3 + 1], v2 = cv[rl * 3 + 2];

    const float4 a = *(const float4*)(x + (size_t)i0 * 16 + q * 4);
    const float4 b = *(const float4*)(x + (size_t)i1 * 16 + q * 4);
    const float4 c = *(const float4*)(x + (size_t)i2 * 16 + q * 4);
    bf16x4 hv;
    hv[0] = (__bf16)(v0 * a.x + v1 * b.x + v2 * c.x);
    hv[1] = (__bf16)(v0 * a.y + v1 * b.y + v2 * c.y);
    hv[2] = (__bf16)(v0 * a.z + v1 * b.z + v2 * c.z);
    hv[3] = (__bf16)(v0 * a.w + v1 * b.w + v2 * c.w);

    const int r   = r0 + rl;
    const int p   = r / 80;              // magic-mul const div
    const int bin = r - p * 80;
    const int cl  = 2 * (bin & 1) + (q >> 1);              // chunk idx within 64-B group
    const int slot = cl ^ ((p >> 1) & 3);
    const size_t off = (size_t)p * 2560 + (bin >> 1) * 64 + slot * 16 + (q & 1) * 8;
    *(bf16x4*)((char*)h + off) = hv;
}

// ---------------------------------------------------------------------------
// GEMM + max-over-t.  512 threads (8 waves, 4x2), tile 256 rows x 256 cols,
// wave tile 64x128 = 4x8 mfma_f32_16x16x32_bf16. Double-buffered LDS,
// one barrier per kstep; next kstep's stage issued AFTER the barrier so the
// barrier's vmcnt(0) drain only covers loads with a full compute phase behind
// them. A and B both chunk-XOR swizzled -> conflict-free ds_read_b128.
// ---------------------------------------------------------------------------
__global__ __launch_bounds__(512, 2) void gemm_max(
    const __bf16* __restrict__ h,
    const __bf16* __restrict__ pw,
    float* __restrict__ out) {

    __shared__ __align__(16) char Abuf[2][16384];   // 256 rows x 64 B
    __shared__ __align__(16) char Bbuf[2][16384];   // 256 cols x 64 B

    const int m    = blockIdx.x >> 1;                // 0..117
    const int ncol = blockIdx.x & 1;                 // 0/1
    const int mbase = m * 256;

    const int tid  = threadIdx.x;
    const int lane = tid & 63;
    const int wave = tid >> 6;
    const int wm = wave >> 1;            // 0..3
    const int wc = wave & 1;             // 0..1

    int a_off[4], b_off[8];
    {
        const int ml = lane & 15, q = lane >> 4;
        const int swz = (q ^ ((ml >> 1) & 3)) << 4;
#pragma unroll
        for (int i = 0; i < 4; ++i)
            a_off[i] = (wm * 64 + i * 16 + ml) * 64 + swz;
#pragma unroll
        for (int j = 0; j < 8; ++j)
            b_off[j] = (wc * 128 + j * 16 + ml) * 64 + swz;
    }

    f32x4 acc[4][8];
#pragma unroll
    for (int i = 0; i < 4; ++i)
#pragma unroll
        for (int j = 0; j < 8; ++j)
            acc[i][j] = (f32x4){0.f, 0.f, 0.f, 0.f};

    // Staging sources (kc-invariant parts). 512 threads: 2 async_ld16 each
    // for A (rows tid>>2 and tid>>2+128) and 2 for B.
    int rA0 = mbase + (tid >> 2);
    int rA1 = rA0 + 128;
    if (rA0 > NP - 1) rA0 = NP - 1;
    if (rA1 > NP - 1) rA1 = NP - 1;
    const char* aSrc0 = (const char*)h + (size_t)rA0 * 2560 + (tid & 3) * 16;
    const char* aSrc1 = (const char*)h + (size_t)rA1 * 2560 + (tid & 3) * 16;
    const char* bSrc  = (const char*)pw + ncol * 16384 + tid * 16;
    const int ldsOff  = tid * 16;

#define STAGE(KC, BUF)                                                  \
    do {                                                                \
        async_ld16(aSrc0 + (KC) * 64, Abuf[BUF] + ldsOff);              \
        async_ld16(aSrc1 + (KC) * 64, Abuf[BUF] + 8192 + ldsOff);       \
        async_ld16(bSrc + (KC) * 32768, Bbuf[BUF] + ldsOff);            \
        async_ld16(bSrc + (KC) * 32768 + 8192, Bbuf[BUF] + 8192 + ldsOff); \
    } while (0)

    STAGE(0, 0);

    for (int kc = 0; kc < KSTEPS; ++kc) {
        __syncthreads();                     // waits on stage(kc) (issued last iter)
        if (kc + 1 < KSTEPS)
            STAGE(kc + 1, (kc + 1) & 1);     // in flight during this kstep's MFMA

        const char* Ab = Abuf[kc & 1];
        const char* Bb = Bbuf[kc & 1];
        bf16x8 af[4], bfr[8];
#pragma unroll
        for (int i = 0; i < 4; ++i)
            af[i] = *(const bf16x8*)(Ab + a_off[i]);
#pragma unroll
        for (int j = 0; j < 8; ++j)
            bfr[j] = *(const bf16x8*)(Bb + b_off[j]);
#pragma unroll
        for (int i = 0; i < 4; ++i)
#pragma unroll
            for (int j = 0; j < 8; ++j)
                acc[i][j] = __builtin_amdgcn_mfma_f32_16x16x32_bf16(
                    af[i], bfr[j], acc[i][j], 0, 0, 0);
    }
#undef STAGE

    // ---- epilogue: max over t (t = col = lane&15), store o = n>>4
    const int rgrp = lane >> 4;
    const int tl   = lane & 15;
#pragma unroll
    for (int i = 0; i < 4; ++i) {
#pragma unroll
        for (int j = 0; j < 8; ++j) {
            float v0 = acc[i][j][0], v1 = acc[i][j][1];
            float v2 = acc[i][j][2], v3 = acc[i][j][3];
#pragma unroll
            for (int off = 1; off < 16; off <<= 1) {
                v0 = fmaxf(v0, __shfl_xor(v0, off));
                v1 = fmaxf(v1, __shfl_xor(v1, off));
                v2 = fmaxf(v2, __shfl_xor(v2, off));
                v3 = fmaxf(v3, __shfl_xor(v3, off));
            }
            if (tl == 0) {
                const int o  = ncol * 16 + wc * 8 + j;
                const int pr = mbase + wm * 64 + i * 16 + rgrp * 4;
                if (pr + 0 < NP) out[(pr + 0) * 32 + o] = v0;
                if (pr + 1 < NP) out[(pr + 1) * 32 + o] = v1;
                if (pr + 2 < NP) out[(pr + 2) * 32 + o] = v2;
                if (pr + 3 < NP) out[(pr + 3) * 32 + o] = v3;
            }
        }
    }
}

extern "C" void kernel_launch(void* const* d_in, const int* in_sizes, int n_in,
                              void* d_out, int out_size, void* d_ws, size_t ws_size,
                              hipStream_t stream) {
    const float* x    = (const float*)d_in[0];
    const int*   cidx = (const int*)d_in[1];
    const float* cval = (const float*)d_in[2];
    const float* w    = (const float*)d_in[3];
    float* out = (float*)d_out;

    __bf16* pw = (__bf16*)d_ws;                               // 1.31 MB
    __bf16* h  = (__bf16*)((char*)d_ws + (2 << 20));          // 76.8 MB @ +2MB

    hipLaunchKernelGGL(prep_weights, dim3(2560), dim3(256), 0, stream, w, pw);
    hipLaunchKernelGGL(gather_h, dim3(NROWS / 64), dim3(256), 0, stream,
                       x, cidx, cval, h);
    hipLaunchKernelGGL(gemm_max, dim3(((NP + 255) / 256) * 2), dim3(512), 0, stream,
                       h, (const __bf16*)pw, out);
}

// Round 5
// 194.772 us; speedup vs baseline: 1.0774x; 1.0774x over previous
//
#include <hip/hip_runtime.h>
#include <hip/hip_bf16.h>
#include <stdint.h>

#define NP 30000
#define BBINS 80
#define INCH 16
#define OUTCH 32
#define KDIM 1280       // BBINS*INCH
#define NDIM 512        // OUTCH*TBINS
#define KSTEPS 40       // KDIM/32
#define NROWS (NP * BBINS)   // 2,400,000

typedef __bf16 bf16x8 __attribute__((ext_vector_type(8)));
typedef __bf16 bf16x4 __attribute__((ext_vector_type(4)));
typedef float f32x4 __attribute__((ext_vector_type(4)));

__device__ __forceinline__ void async_ld16(const void* g, void* l) {
    __builtin_amdgcn_global_load_lds(
        (const __attribute__((address_space(1))) unsigned int*)g,
        (__attribute__((address_space(3))) unsigned int*)l,
        16, 0, 0);
}

// ---------------------------------------------------------------------------
// Prep: PW[kc][n][slot][e] bf16; slot s holds data k-chunk s ^ ((n>>1)&3)
// (conflict-free ds_read_b128 B fragments). lw[k][n] = W[(b+5t)%80][c][o],
// k=b*16+c, n=o*16+t.
// ---------------------------------------------------------------------------
__global__ void prep_weights(const float* __restrict__ w, __bf16* __restrict__ pw) {
    int gid = blockIdx.x * 256 + threadIdx.x;           // 655360 total
    int e  = gid & 7;
    int qs = (gid >> 3) & 3;                             // slot
    int n  = (gid >> 5) & 511;
    int kc = gid >> 14;                                  // 0..39
    int kp = kc * 32 + ((qs ^ ((n >> 1) & 3)) << 3) + e; // data k index
    int b = kp >> 4, c = kp & 15;
    int o = n >> 4,  t = n & 15;
    int bid = (b + 5 * t) % BBINS;
    pw[gid] = (__bf16)w[(bid * INCH + c) * OUTCH + o];
}

// ---------------------------------------------------------------------------
// Gather: block = 256 threads <-> 64 rows (4 lanes/row). Conn staged to LDS
// with coalesced dwordx4, broadcast-read back. x loads: 4 contiguous lanes
// per 64-B x row -> 16 lines/instr. h written in the GEMM-ready swizzled
// layout (chunk-XOR within 64-B groups); stores stay line-coalesced.
// ---------------------------------------------------------------------------
__global__ __launch_bounds__(256) void gather_h(
    const float* __restrict__ x,
    const int*   __restrict__ cidx,
    const float* __restrict__ cval,
    __bf16* __restrict__ h) {
    __shared__ int   ci[192];
    __shared__ float cv[192];
    const int t  = threadIdx.x;
    const int r0 = blockIdx.x * 64;

    if (t < 48)
        ((int4*)ci)[t] = ((const int4*)(cidx + (size_t)r0 * 3))[t];
    else if (t >= 64 && t < 112)
        ((float4*)cv)[t - 64] = ((const float4*)(cval + (size_t)r0 * 3))[t - 64];
    __syncthreads();

    const int rl = t >> 2;               // 0..63
    const int q  = t & 3;                // channel quad
    const int i0 = ci[rl * 3 + 0], i1 = ci[rl * 3 + 1], i2 = ci[rl * 3 + 2];
    const float v0 = cv[rl * 3 + 0], v1 = cv[rl * 3 + 1], v2 = cv[rl * 3 + 2];

    const float4 a = *(const float4*)(x + (size_t)i0 * 16 + q * 4);
    const float4 b = *(const float4*)(x + (size_t)i1 * 16 + q * 4);
    const float4 c = *(const float4*)(x + (size_t)i2 * 16 + q * 4);
    bf16x4 hv;
    hv[0] = (__bf16)(v0 * a.x + v1 * b.x + v2 * c.x);
    hv[1] = (__bf16)(v0 * a.y + v1 * b.y + v2 * c.y);
    hv[2] = (__bf16)(v0 * a.z + v1 * b.z + v2 * c.z);
    hv[3] = (__bf16)(v0 * a.w + v1 * b.w + v2 * c.w);

    const int r   = r0 + rl;
    const int p   = r / 80;              // magic-mul const div
    const int bin = r - p * 80;
    const int cl  = 2 * (bin & 1) + (q >> 1);              // chunk within 64-B group
    const int slot = cl ^ ((p >> 1) & 3);
    const size_t off = (size_t)p * 2560 + (bin >> 1) * 64 + slot * 16 + (q & 1) * 8;
    *(bf16x4*)((char*)h + off) = hv;
}

// ---------------------------------------------------------------------------
// GEMM + max-over-t.  256 threads (4 waves, 2x2), tile 128 rows x 256 cols,
// wave tile 64x128 = 4x8 mfma_f32_16x16x32_bf16. Double-buffered LDS (48 KB
// -> ~2 blocks/CU resident), ONE barrier per kstep, next stage issued right
// after the barrier so its latency is covered by this kstep's compute and by
// the co-resident block (m114 overlap). Conflict-free chunk-XOR swizzle on
// both A and B (verified: SQ_LDS_BANK_CONFLICT = 0).
// Grid 480, XCD-pair swizzle: bids g and g+8 (same XCD slot) are the two
// ncol halves of one m-block, sharing the A rows in that XCD's L2.
// ---------------------------------------------------------------------------
__global__ __launch_bounds__(256, 2) void gemm_max(
    const __bf16* __restrict__ h,
    const __bf16* __restrict__ pw,
    float* __restrict__ out) {

    __shared__ __align__(16) char Abuf[2][8192];    // 128 rows x 64 B
    __shared__ __align__(16) char Bbuf[2][16384];   // 256 cols x 64 B

    const int bid = blockIdx.x;
    const int m    = (bid >> 4) * 8 + (bid & 7);     // 0..239
    const int ncol = (bid >> 3) & 1;                 // 0/1
    if (m >= 235) return;                            // 10 dead pad blocks
    const int mbase = m * 128;

    const int tid  = threadIdx.x;
    const int lane = tid & 63;
    const int wave = tid >> 6;
    const int wm = wave >> 1;            // 0..1
    const int wc = wave & 1;             // 0..1

    int a_off[4], b_off[8];
    {
        const int ml = lane & 15, q = lane >> 4;
        const int swz = (q ^ ((ml >> 1) & 3)) << 4;
#pragma unroll
        for (int i = 0; i < 4; ++i)
            a_off[i] = (wm * 64 + i * 16 + ml) * 64 + swz;
#pragma unroll
        for (int j = 0; j < 8; ++j)
            b_off[j] = (wc * 128 + j * 16 + ml) * 64 + swz;
    }

    f32x4 acc[4][8];
#pragma unroll
    for (int i = 0; i < 4; ++i)
#pragma unroll
        for (int j = 0; j < 8; ++j)
            acc[i][j] = (f32x4){0.f, 0.f, 0.f, 0.f};

    // Staging sources (kc-invariant parts). 256 threads: 2 async_ld16 for A
    // (rows tid>>2 and tid>>2+64), 4 for B.
    int rA0 = mbase + (tid >> 2);
    int rA1 = rA0 + 64;
    if (rA0 > NP - 1) rA0 = NP - 1;
    if (rA1 > NP - 1) rA1 = NP - 1;
    const char* aSrc0 = (const char*)h + (size_t)rA0 * 2560 + (tid & 3) * 16;
    const char* aSrc1 = (const char*)h + (size_t)rA1 * 2560 + (tid & 3) * 16;
    const char* bSrc  = (const char*)pw + ncol * 16384 + tid * 16;
    const int ldsOff  = tid * 16;

#define STAGE(KC, BUF)                                                     \
    do {                                                                   \
        async_ld16(aSrc0 + (KC) * 64, Abuf[BUF] + ldsOff);                 \
        async_ld16(aSrc1 + (KC) * 64, Abuf[BUF] + 4096 + ldsOff);          \
        async_ld16(bSrc + (KC) * 32768,         Bbuf[BUF] + ldsOff);       \
        async_ld16(bSrc + (KC) * 32768 + 4096,  Bbuf[BUF] + 4096 + ldsOff); \
        async_ld16(bSrc + (KC) * 32768 + 8192,  Bbuf[BUF] + 8192 + ldsOff); \
        async_ld16(bSrc + (KC) * 32768 + 12288, Bbuf[BUF] + 12288 + ldsOff);\
    } while (0)

    STAGE(0, 0);

    for (int kc = 0; kc < KSTEPS; ++kc) {
        __syncthreads();                     // drains stage(kc) (issued last iter)
        if (kc + 1 < KSTEPS)
            STAGE(kc + 1, (kc + 1) & 1);     // in flight during this kstep's MFMA

        const char* Ab = Abuf[kc & 1];
        const char* Bb = Bbuf[kc & 1];
        bf16x8 af[4], bfr[8];
#pragma unroll
        for (int i = 0; i < 4; ++i)
            af[i] = *(const bf16x8*)(Ab + a_off[i]);
#pragma unroll
        for (int j = 0; j < 8; ++j)
            bfr[j] = *(const bf16x8*)(Bb + b_off[j]);
#pragma unroll
        for (int i = 0; i < 4; ++i)
#pragma unroll
            for (int j = 0; j < 8; ++j)
                acc[i][j] = __builtin_amdgcn_mfma_f32_16x16x32_bf16(
                    af[i], bfr[j], acc[i][j], 0, 0, 0);
    }
#undef STAGE

    // ---- epilogue: max over t (t = col = lane&15), store o = n>>4
    const int rgrp = lane >> 4;
    const int tl   = lane & 15;
#pragma unroll
    for (int i = 0; i < 4; ++i) {
#pragma unroll
        for (int j = 0; j < 8; ++j) {
            float v0 = acc[i][j][0], v1 = acc[i][j][1];
            float v2 = acc[i][j][2], v3 = acc[i][j][3];
#pragma unroll
            for (int off = 1; off < 16; off <<= 1) {
                v0 = fmaxf(v0, __shfl_xor(v0, off));
                v1 = fmaxf(v1, __shfl_xor(v1, off));
                v2 = fmaxf(v2, __shfl_xor(v2, off));
                v3 = fmaxf(v3, __shfl_xor(v3, off));
            }
            if (tl == 0) {
                const int o  = ncol * 16 + wc * 8 + j;
                const int pr = mbase + wm * 64 + i * 16 + rgrp * 4;
                if (pr + 0 < NP) out[(pr + 0) * 32 + o] = v0;
                if (pr + 1 < NP) out[(pr + 1) * 32 + o] = v1;
                if (pr + 2 < NP) out[(pr + 2) * 32 + o] = v2;
                if (pr + 3 < NP) out[(pr + 3) * 32 + o] = v3;
            }
        }
    }
}

extern "C" void kernel_launch(void* const* d_in, const int* in_sizes, int n_in,
                              void* d_out, int out_size, void* d_ws, size_t ws_size,
                              hipStream_t stream) {
    const float* x    = (const float*)d_in[0];
    const int*   cidx = (const int*)d_in[1];
    const float* cval = (const float*)d_in[2];
    const float* w    = (const float*)d_in[3];
    float* out = (float*)d_out;

    __bf16* pw = (__bf16*)d_ws;                               // 1.31 MB
    __bf16* h  = (__bf16*)((char*)d_ws + (2 << 20));          // 76.8 MB @ +2MB

    hipLaunchKernelGGL(prep_weights, dim3(2560), dim3(256), 0, stream, w, pw);
    hipLaunchKernelGGL(gather_h, dim3(NROWS / 64), dim3(256), 0, stream,
                       x, cidx, cval, h);
    hipLaunchKernelGGL(gemm_max, dim3(480), dim3(256), 0, stream,
                       h, (const __bf16*)pw, out);
}